// Round 12
// baseline (1102.911 us; speedup 1.0000x reference)
//
#include <hip/hip_runtime.h>
#include <hip/hip_bf16.h>
#include <stdint.h>

// SJ_SNN: bit-exact replica of the golden (jax on CPU -> XLA/Eigen fp32):
// per output element the contraction is a SINGLE accumulator, ascending k,
// true FMA. PASS r6..r12/r16/r18/r19 (absmax 0.00390625 = bf16 floor).
// r20 = r19 (best, 1038us) + ONE change: 16x8-tile GEMM retried with
// __launch_bounds__(256,1).
// r17's 16x8 failed via VGPR SPILL, not model error: VGPR_Count pinned at
// the 128 granule with ~127MB scratch WRITE (compiler targeted 4 waves/EU).
// (256,1) permits up to 512 VGPR; needed ~200. Model (never refuted):
// 6 ds_read_b128 / 128 FMA -> LDS:FMA ratio 1.125 (vs 1.5 for 8x8) at
// 8 waves/CU -> ~330-370us vs 402.
// Pre-committed fork: VGPR=128 + WRITE>200MB again => 16x8 permanently
// closed, revert r10 GEMM, declare roofline (all blocks at verified floors).

__global__ void k_zero(unsigned int* __restrict__ p, int n){
  int i = blockIdx.x * 256 + threadIdx.x;
  if (i < n) p[i] = 0u;
}

// out[C][R] = in[R][C]  (exact fp32 copy)
__global__ void k_transpose(const float* __restrict__ in, float* __restrict__ out, int R, int C){
  __shared__ float tile[32][33];
  int bx = blockIdx.x * 32, by = blockIdx.y * 32;
  int tx = threadIdx.x, ty = threadIdx.y;
  for (int i = ty; i < 32; i += 8)
    tile[i][tx] = in[(size_t)(by + i) * C + bx + tx];
  __syncthreads();
  for (int i = ty; i < 32; i += 8)
    out[(size_t)(bx + i) * R + by + tx] = tile[tx][i];
}

// Layer-0 GEMM, Eigen order: C[m][e] = (single ascending FMA chain over
// k=0..511 of x[m][k]*W0[e][k]) + bias[e].
// 256(m) x 128(n) block tile, 16x8 per thread, 256 threads (r17 structure,
// correctness-verified; r20: launch_bounds (256,2)->(256,1) to kill spill).
// Lane remap: c = tid bits {0,1,2,6} (8 cols), r = tid bits {3,4,5,7}
// (16 rows). As = [32 k][260], Bs = [32 k][132];
// slot(k,col) = G*4 + (col&3), G = (col>>2)^(col>>5)^(k>>3).
__global__ __launch_bounds__(256, 1) void k_gemm_np(const float* __restrict__ A,
    const float* __restrict__ Bw, const float* __restrict__ bias,
    float* __restrict__ C, int M){
  (void)M;
  __shared__ float LDS[32 * 260 + 32 * 132];
  float* As = LDS;                 // [32][260]
  float* Bs = LDS + 32 * 260;      // [32][132]
  int bm = blockIdx.y * 256;
  int bn = blockIdx.x * 128;
  int tid = threadIdx.x;
  int kk = tid & 31, q = tid >> 5;                 // staging decode (q 0..7)
  int c = (tid & 7) | ((tid & 64) >> 3);           // 0..15
  int r = ((tid >> 3) & 7) | ((tid & 128) >> 4);   // 0..15
  int gA = (4 * r) ^ (r >> 1);                     // G(k=0, col=r*16)
  int gB = (2 * c) ^ (c >> 2);                     // G(k=0, col=c*8)
  float acc[16][8];
#pragma unroll
  for (int ii = 0; ii < 16; ++ii)
#pragma unroll
    for (int jj = 0; jj < 8; ++jj) acc[ii][jj] = 0.f;

  for (int k0 = 0; k0 < 512; k0 += 32){
    // stage A: 8 col-groups of 4 (cols 0..255)
#pragma unroll
    for (int rr = 0; rr < 8; ++rr){
      int colb = q * 4 + rr * 32;                  // 4-aligned, 0..252
      int gi = (colb >> 2) ^ (colb >> 5) ^ (kk >> 3);
      float4 va;
      va.x = A[(size_t)(bm + colb + 0) * 512 + k0 + kk];
      va.y = A[(size_t)(bm + colb + 1) * 512 + k0 + kk];
      va.z = A[(size_t)(bm + colb + 2) * 512 + k0 + kk];
      va.w = A[(size_t)(bm + colb + 3) * 512 + k0 + kk];
      *(float4*)&As[kk * 260 + (gi << 2)] = va;
    }
    // stage B: 4 col-groups of 4 (cols 0..127)
#pragma unroll
    for (int rr = 0; rr < 4; ++rr){
      int colb = q * 4 + rr * 32;
      int gi = (colb >> 2) ^ (colb >> 5) ^ (kk >> 3);
      float4 vb;
      vb.x = Bw[(size_t)(bn + colb + 0) * 512 + k0 + kk];
      vb.y = Bw[(size_t)(bn + colb + 1) * 512 + k0 + kk];
      vb.z = Bw[(size_t)(bn + colb + 2) * 512 + k0 + kk];
      vb.w = Bw[(size_t)(bn + colb + 3) * 512 + k0 + kk];
      *(float4*)&Bs[kk * 132 + (gi << 2)] = vb;
    }
    __syncthreads();
    // compute: ascending k overall (kg outer ascending, k8 inner ascending)
#pragma unroll
    for (int kg = 0; kg < 4; ++kg){
      const int sa = (gA ^ kg) << 2;
      const int sb = (gB ^ kg) << 2;
#pragma unroll
      for (int k8 = 0; k8 < 8; ++k8){
        const int k = kg * 8 + k8;
        float4 av0 = *(const float4*)&As[k * 260 + sa];
        float4 av1 = *(const float4*)&As[k * 260 + (sa ^ 4)];
        float4 av2 = *(const float4*)&As[k * 260 + (sa ^ 8)];
        float4 av3 = *(const float4*)&As[k * 260 + (sa ^ 12)];
        float4 bv0 = *(const float4*)&Bs[k * 132 + sb];
        float4 bv1 = *(const float4*)&Bs[k * 132 + (sb ^ 4)];
        float a[16] = {av0.x, av0.y, av0.z, av0.w, av1.x, av1.y, av1.z, av1.w,
                       av2.x, av2.y, av2.z, av2.w, av3.x, av3.y, av3.z, av3.w};
        float b[8]  = {bv0.x, bv0.y, bv0.z, bv0.w, bv1.x, bv1.y, bv1.z, bv1.w};
#pragma unroll
        for (int ii = 0; ii < 16; ++ii)
#pragma unroll
          for (int jj = 0; jj < 8; ++jj)
            acc[ii][jj] = __fmaf_rn(a[ii], b[jj], acc[ii][jj]);
      }
    }
    __syncthreads();
  }

  // Epilogue: bias + LDS-staged coalesced stores. 4 rounds of 64 rows x 128
  // cols through LDS chunk [64][132]. Participating threads in round t:
  // (r>>2)==t; chunk row lr = (r&3)*16 + ii. (r17-verified correct.)
  float4 bi0 = *(const float4*)(bias + bn + c * 8);
  float4 bi1 = *(const float4*)(bias + bn + c * 8 + 4);
#pragma unroll
  for (int t = 0; t < 4; ++t){
    if ((r >> 2) == t){
#pragma unroll
      for (int ii = 0; ii < 16; ++ii){
        const int lr = (r & 3) * 16 + ii;
        float4 o0, o1;
        o0.x = __fadd_rn(acc[ii][0], bi0.x);
        o0.y = __fadd_rn(acc[ii][1], bi0.y);
        o0.z = __fadd_rn(acc[ii][2], bi0.z);
        o0.w = __fadd_rn(acc[ii][3], bi0.w);
        o1.x = __fadd_rn(acc[ii][4], bi1.x);
        o1.y = __fadd_rn(acc[ii][5], bi1.y);
        o1.z = __fadd_rn(acc[ii][6], bi1.z);
        o1.w = __fadd_rn(acc[ii][7], bi1.w);
        *(float4*)&LDS[lr * 132 + c * 8]     = o0;
        *(float4*)&LDS[lr * 132 + c * 8 + 4] = o1;
      }
    }
    __syncthreads();
#pragma unroll
    for (int u = 0; u < 8; ++u){
      int idx = u * 256 + tid;
      int row = idx >> 5;
      int ch4 = (idx & 31) << 2;
      float4 v = *(const float4*)&LDS[row * 132 + ch4];
      *(float4*)&C[(size_t)(bm + t * 64 + row) * 1024 + bn + ch4] = v;
    }
    __syncthreads();
  }
}

// BN stats: per (chunk, channel), SEQUENTIAL in-order over 256 samples.
// Computes rstd once per (chunk,channel) (r18 hoist) -> bit-exact.
__global__ __launch_bounds__(256) void k_stats_np(const float* __restrict__ A,
    float* __restrict__ mu, float* __restrict__ rstd, int Dch, int c0){
  int cl = blockIdx.x;
  int ch = blockIdx.y * 256 + threadIdx.x;
  const float* base = A + (size_t)cl * 256 * Dch + ch;
  float acc = 0.f;
  for (int s = 0; s < 256; ++s)
    acc = __fadd_rn(acc, base[(size_t)s * Dch]);
  float m = __fmul_rn(acc, 1.f / 256.f);   // /256 exact (pow2)
  float vacc = 0.f;
  for (int s = 0; s < 256; ++s){
    float d = __fsub_rn(base[(size_t)s * Dch], m);
    vacc = __fadd_rn(vacc, __fmul_rn(d, d));
  }
  float var = __fmul_rn(vacc, 1.f / 256.f);
  float ve  = __fadd_rn(var, 1e-5f);
  float sq  = (float)sqrt((double)ve);         // correctly-rounded fp32 sqrt
  float r   = (float)(1.0 / (double)sq);       // correctly-rounded fp32 div
  int c = c0 + cl;
  mu[(size_t)c * Dch + ch]   = m;
  rstd[(size_t)c * Dch + ch] = r;
}

// fp32 BN + LIF scan (hidden layers): spike bitmasks, 64-thread blocks.
// r19: 2-phase even/odd chunk loop; next chunk's h + mu/rstd prefetched
// before processing current chunk (pure load scheduling; bit-exact).
__global__ __launch_bounds__(64) void k_scan_spike_np(const float* __restrict__ A,
    const float* __restrict__ mu, const float* __restrict__ rstd,
    const float* __restrict__ g, const float* __restrict__ bt,
    float* __restrict__ vstate, unsigned long long* __restrict__ mask,
    int Dch, int c0, int nb){
  int ebn = Dch >> 6;
  int eb = blockIdx.x % ebn;
  int b  = blockIdx.x / ebn;
  int e  = (eb << 6) + threadIdx.x;
  float gg = g[e], bb = bt[e];
  float v = vstate[(size_t)b * Dch + e];
  float hA[8], hB[8];
#pragma unroll
  for (int t = 0; t < 8; ++t)
    hA[t] = A[(size_t)(t * 32 + b) * Dch + e];
  float mN = mu[(size_t)c0 * Dch + e];
  float rN = rstd[(size_t)c0 * Dch + e];

  for (int cl = 0; cl < nb; cl += 2){
    // ---- even chunk cl: consumes hA, mN/rN; prefetch chunk cl+1 ----
    {
      float mC = mN, rC = rN;
      if (cl + 1 < nb){
#pragma unroll
        for (int t = 0; t < 8; ++t)
          hB[t] = A[(size_t)(((cl + 1) * 8 + t) * 32 + b) * Dch + e];
        mN = mu[(size_t)(c0 + cl + 1) * Dch + e];
        rN = rstd[(size_t)(c0 + cl + 1) * Dch + e];
      }
#pragma unroll
      for (int t = 0; t < 8; ++t){
        int sl = (cl * 8 + t) * 32 + b;
        float xn = __fadd_rn(__fmul_rn(__fmul_rn(gg, __fsub_rn(hA[t], mC)), rC), bb);
        v = __fadd_rn(v, __fmul_rn(__fsub_rn(xn, v), 0.5f));
        bool sp = (v >= 1.0f);                   // == (v-1>=0)
        unsigned long long bal = __ballot(sp);
        if (sp) v = 0.0f;
        if (threadIdx.x == 0) mask[(size_t)sl * 16 + eb] = bal;
      }
    }
    // ---- odd chunk cl+1: consumes hB, mN/rN; prefetch chunk cl+2 ----
    if (cl + 1 < nb){
      float mC = mN, rC = rN;
      if (cl + 2 < nb){
#pragma unroll
        for (int t = 0; t < 8; ++t)
          hA[t] = A[(size_t)(((cl + 2) * 8 + t) * 32 + b) * Dch + e];
        mN = mu[(size_t)(c0 + cl + 2) * Dch + e];
        rN = rstd[(size_t)(c0 + cl + 2) * Dch + e];
      }
#pragma unroll
      for (int t = 0; t < 8; ++t){
        int sl = ((cl + 1) * 8 + t) * 32 + b;
        float xn = __fadd_rn(__fmul_rn(__fmul_rn(gg, __fsub_rn(hB[t], mC)), rC), bb);
        v = __fadd_rn(v, __fmul_rn(__fsub_rn(xn, v), 0.5f));
        bool sp = (v >= 1.0f);
        unsigned long long bal = __ballot(sp);
        if (sp) v = 0.0f;
        if (threadIdx.x == 0) mask[(size_t)sl * 16 + eb] = bal;
      }
    }
  }
  vstate[(size_t)b * Dch + e] = v;
}

// Sparse spike linear, Eigen order. Wave-cooperative list extraction:
// 16 lanes popcount their 64-bit mask word, __shfl exclusive prefix-scan,
// then parallel ascending writes into LDS. List order identical to the old
// serial scan -> single-accumulator ascending add chain preserved exactly.
// Consume loop: 8 weight rows in flight.
__global__ __launch_bounds__(256) void k_sparse_np(const unsigned long long* __restrict__ mask,
    const float* __restrict__ WT, const float* __restrict__ bias,
    float* __restrict__ C, int Dout){
  int tid = threadIdx.x;
  int lane = tid & 63;
  int wid = tid >> 6;
  int wps = Dout >> 8;            // waves per sample: 4 (1024) or 2 (512)
  int chgrp = wid % wps;
  int sgrp  = wid / wps;
  int spb   = 4 / wps;            // samples per block
  int s = blockIdx.x * spb + sgrp;
  int ch = (chgrp << 8) + (lane << 2);
  __shared__ unsigned short list[2][1024];
  __shared__ int nlist[2];

  if (chgrp == 0 && lane < 16){
    unsigned long long mw = mask[(size_t)s * 16 + lane];
    int cnt = __popcll(mw);
    int base = 0;
#pragma unroll
    for (int w = 0; w < 16; ++w){
      int cw = __shfl(cnt, w, 64);
      base += (w < lane) ? cw : 0;
    }
    int idx = base;
    while (mw){
      int bit = __ffsll(mw) - 1;
      mw &= mw - 1;
      list[sgrp][idx++] = (unsigned short)((lane << 6) + bit);
    }
    if (lane == 15) nlist[sgrp] = base + cnt;
  }
  __syncthreads();
  int n = nlist[sgrp];
  const unsigned short* il = list[sgrp];
  float a0 = 0.f, a1 = 0.f, a2 = 0.f, a3 = 0.f;
  int i = 0;
  for (; i + 8 <= n; i += 8){
    float4 wv[8];
#pragma unroll
    for (int u = 0; u < 8; ++u)
      wv[u] = *(const float4*)(WT + (size_t)il[i + u] * Dout + ch);
#pragma unroll
    for (int u = 0; u < 8; ++u){
      a0 = __fadd_rn(a0, wv[u].x); a1 = __fadd_rn(a1, wv[u].y);
      a2 = __fadd_rn(a2, wv[u].z); a3 = __fadd_rn(a3, wv[u].w);
    }
  }
  for (; i < n; ++i){
    int d = il[i];
    float4 wv = *(const float4*)(WT + (size_t)d * Dout + ch);
    a0 = __fadd_rn(a0, wv.x); a1 = __fadd_rn(a1, wv.y); a2 = __fadd_rn(a2, wv.z); a3 = __fadd_rn(a3, wv.w);
  }
  float4 bb = *(const float4*)(bias + ch);
  float4 o;
  o.x = __fadd_rn(a0, bb.x);
  o.y = __fadd_rn(a1, bb.y);
  o.z = __fadd_rn(a2, bb.z);
  o.w = __fadd_rn(a3, bb.w);
  *(float4*)(C + (size_t)s * Dout + ch) = o;
}

// Last layer: fp32 leaky integrator; sequential mean over 8 timesteps,
// /8 exact; float32 out. r19: same 2-phase prefetch as spike scan.
__global__ __launch_bounds__(64) void k_scan_last_np(const float* __restrict__ A,
    const float* __restrict__ mu, const float* __restrict__ rstd,
    const float* __restrict__ g, const float* __restrict__ bt,
    float* __restrict__ vstate, float* __restrict__ out, int c0, int nb){
  const int Dch = 512;
  int eb = blockIdx.x & 7;
  int b  = blockIdx.x >> 3;
  int e  = (eb << 6) + threadIdx.x;
  float gg = g[e], bb = bt[e];
  float v = vstate[(size_t)b * Dch + e];
  float hA[8], hB[8];
#pragma unroll
  for (int t = 0; t < 8; ++t)
    hA[t] = A[(size_t)(t * 32 + b) * Dch + e];
  float mN = mu[(size_t)c0 * Dch + e];
  float rN = rstd[(size_t)c0 * Dch + e];

  for (int cl = 0; cl < nb; cl += 2){
    // ---- even chunk cl ----
    {
      float mC = mN, rC = rN;
      if (cl + 1 < nb){
#pragma unroll
        for (int t = 0; t < 8; ++t)
          hB[t] = A[(size_t)(((cl + 1) * 8 + t) * 32 + b) * Dch + e];
        mN = mu[(size_t)(c0 + cl + 1) * Dch + e];
        rN = rstd[(size_t)(c0 + cl + 1) * Dch + e];
      }
      float macc = 0.f;
#pragma unroll
      for (int t = 0; t < 8; ++t){
        float xn = __fadd_rn(__fmul_rn(__fmul_rn(gg, __fsub_rn(hA[t], mC)), rC), bb);
        v = __fadd_rn(v, __fmul_rn(__fsub_rn(xn, v), 0.5f));
        macc = __fadd_rn(macc, v);
      }
      out[((size_t)(c0 + cl) * 32 + b) * 512 + e] = __fmul_rn(macc, 0.125f);
    }
    // ---- odd chunk cl+1 ----
    if (cl + 1 < nb){
      float mC = mN, rC = rN;
      if (cl + 2 < nb){
#pragma unroll
        for (int t = 0; t < 8; ++t)
          hA[t] = A[(size_t)(((cl + 2) * 8 + t) * 32 + b) * Dch + e];
        mN = mu[(size_t)(c0 + cl + 2) * Dch + e];
        rN = rstd[(size_t)(c0 + cl + 2) * Dch + e];
      }
      float macc = 0.f;
#pragma unroll
      for (int t = 0; t < 8; ++t){
        float xn = __fadd_rn(__fmul_rn(__fmul_rn(gg, __fsub_rn(hB[t], mC)), rC), bb);
        v = __fadd_rn(v, __fmul_rn(__fsub_rn(xn, v), 0.5f));
        macc = __fadd_rn(macc, v);
      }
      out[((size_t)(c0 + cl + 1) * 32 + b) * 512 + e] = __fmul_rn(macc, 0.125f);
    }
  }
  vstate[(size_t)b * Dch + e] = v;
}

static inline size_t al256(size_t x){ return (x + 255) & ~(size_t)255; }

extern "C" void kernel_launch(void* const* d_in, const int* in_sizes, int n_in,
                              void* d_out, int out_size, void* d_ws, size_t ws_size,
                              hipStream_t stream){
  (void)in_sizes; (void)n_in; (void)out_size;
  const float* x   = (const float*)d_in[0];
  const float* W0  = (const float*)d_in[1];
  const float* b0  = (const float*)d_in[2];
  const float* g0  = (const float*)d_in[3];
  const float* bt0 = (const float*)d_in[4];
  const float* W1  = (const float*)d_in[5];
  const float* b1  = (const float*)d_in[6];
  const float* g1  = (const float*)d_in[7];
  const float* bt1 = (const float*)d_in[8];
  const float* W2  = (const float*)d_in[9];
  const float* b2  = (const float*)d_in[10];
  const float* g2  = (const float*)d_in[11];
  const float* bt2 = (const float*)d_in[12];
  float* out = (float*)d_out;   // reference output dtype: float32

  char* p = (char*)d_ws;
  auto carve = [&](size_t bytes)->char*{ char* q = p; p += al256(bytes); return q; };
  float* W1T  = (float*)carve((size_t)1024 * 1024 * 4);   // [d=1024][e=1024]
  float* W2T  = (float*)carve((size_t)1024 * 512 * 4);    // [d=1024][e=512]
  float* mu0  = (float*)carve((size_t)128 * 1024 * 4);
  float* rs0  = (float*)carve((size_t)128 * 1024 * 4);
  float* mu1  = (float*)carve((size_t)128 * 1024 * 4);
  float* rs1  = (float*)carve((size_t)128 * 1024 * 4);
  float* mu2  = (float*)carve((size_t)128 * 512 * 4);
  float* rs2  = (float*)carve((size_t)128 * 512 * 4);
  float* v0   = (float*)carve((size_t)32 * 1024 * 4);
  float* v1   = (float*)carve((size_t)32 * 1024 * 4);
  float* v2   = (float*)carve((size_t)32 * 512 * 4);
  size_t fixed_used = (size_t)(p - (char*)d_ws);

  auto need = [&](int nb)->size_t{
    return al256((size_t)nb * 256 * 1024 * 4)        // fp32 activation buffer
         + 2 * al256((size_t)nb * 256 * 16 * 8);     // mask0, mask1
  };
  int NB = 128;
  while (NB > 1 && fixed_used + need(NB) > ws_size) NB >>= 1;
  if (fixed_used + need(NB) > ws_size) return;

  float*              a_buf = (float*)carve((size_t)NB * 256 * 1024 * 4);
  unsigned long long* mask0 = (unsigned long long*)carve((size_t)NB * 256 * 16 * 8);
  unsigned long long* mask1 = (unsigned long long*)carve((size_t)NB * 256 * 16 * 8);

  // zero v-states (carved contiguously: 32*(1024+1024+512) floats)
  {
    int nz = 32 * (1024 + 1024 + 512);
    k_zero<<<dim3((nz + 255) / 256), dim3(256), 0, stream>>>((unsigned int*)v0, nz);
  }
  k_transpose<<<dim3(32, 32), dim3(32, 8), 0, stream>>>(W1, W1T, 1024, 1024);
  k_transpose<<<dim3(32, 16), dim3(32, 8), 0, stream>>>(W2, W2T, 512, 1024);

  int nblk = 128 / NB;
  for (int cb = 0; cb < nblk; ++cb){
    int c0 = cb * NB;
    int M = NB * 256;
    const float* xblk = x + (size_t)c0 * 256 * 512;

    // Layer 0 (Eigen-order FMA GEMM; n-tile-major grid for x L2 reuse)
    k_gemm_np<<<dim3(8, M / 256), dim3(256), 0, stream>>>(xblk, W0, b0, a_buf, M);
    k_stats_np<<<dim3(NB, 4), dim3(256), 0, stream>>>(a_buf, mu0, rs0, 1024, c0);
    k_scan_spike_np<<<dim3(32 * 16), dim3(64), 0, stream>>>(a_buf, mu0, rs0, g0, bt0, v0, mask0, 1024, c0, NB);

    // Layer 1 (sparse, ascending single-chain, batched loads)
    k_sparse_np<<<dim3(M), dim3(256), 0, stream>>>(mask0, W1T, b1, a_buf, 1024);
    k_stats_np<<<dim3(NB, 4), dim3(256), 0, stream>>>(a_buf, mu1, rs1, 1024, c0);
    k_scan_spike_np<<<dim3(32 * 16), dim3(64), 0, stream>>>(a_buf, mu1, rs1, g1, bt1, v1, mask1, 1024, c0, NB);

    // Layer 2 (sparse) + integrator output
    k_sparse_np<<<dim3(M / 2), dim3(256), 0, stream>>>(mask1, W2T, b2, a_buf, 512);
    k_stats_np<<<dim3(NB, 2), dim3(256), 0, stream>>>(a_buf, mu2, rs2, 512, c0);
    k_scan_last_np<<<dim3(32 * 8), dim3(64), 0, stream>>>(a_buf, mu2, rs2, g2, bt2, v2, out, c0, NB);
  }
}

// Round 13
// 1055.556 us; speedup vs baseline: 1.0449x; 1.0449x over previous
//
#include <hip/hip_runtime.h>
#include <hip/hip_bf16.h>
#include <stdint.h>

// SJ_SNN: bit-exact replica of the golden (jax on CPU -> XLA/Eigen fp32):
// per output element the contraction is a SINGLE accumulator, ascending k,
// true FMA. PASS r6..r12/r16/r18/r19 (absmax 0.00390625 = bf16 floor).
// r21 = r19 restored verbatim (measured best: 1038.4 us).
// FINAL LEDGER of refuted alternatives:
//  - r9 direct scattered C stores: L2 RMW, WRITE 4.3x -> LDS-staged epilogue.
//  - r11 SGPR-B 256x16 wave tile: L1 port ~96 B/cyc > 64 -> 431us.
//  - r13/r15 grouped sparse: compiler predication = dense adds + acc spill.
//  - r17 16x8 @(256,2): VGPR pinned 128 + scratch spill -> 483us.
//  - r20 16x8 @(256,1): spill cured (144 VGPR) but 1 block/CU -> barrier/LDS
//    latency exposed -> 547us. 16x8 closed in both regimes.
// Verified floors: GEMM 402us (LDS-issue bound; no fp32 MFMA on CDNA4),
// sparse ~420us (L2-BW on weight rows), scans (latency chains, prefetched),
// stats (BW). Total 1038us.

__global__ void k_zero(unsigned int* __restrict__ p, int n){
  int i = blockIdx.x * 256 + threadIdx.x;
  if (i < n) p[i] = 0u;
}

// out[C][R] = in[R][C]  (exact fp32 copy)
__global__ void k_transpose(const float* __restrict__ in, float* __restrict__ out, int R, int C){
  __shared__ float tile[32][33];
  int bx = blockIdx.x * 32, by = blockIdx.y * 32;
  int tx = threadIdx.x, ty = threadIdx.y;
  for (int i = ty; i < 32; i += 8)
    tile[i][tx] = in[(size_t)(by + i) * C + bx + tx];
  __syncthreads();
  for (int i = ty; i < 32; i += 8)
    out[(size_t)(bx + i) * R + by + tx] = tile[tx][i];
}

// Layer-0 GEMM, Eigen order: C[m][e] = (single ascending FMA chain over
// k=0..511 of x[m][k]*W0[e][k]) + bias[e].
// 128(m) x 128(n) block tile, 8x8 per thread, 256 threads. (r10 structure,
// verified 402us / VALUBusy ~75 / conflicts 1.05e6 / WRITE 131MB.)
__global__ __launch_bounds__(256, 4) void k_gemm_np(const float* __restrict__ A,
    const float* __restrict__ Bw, const float* __restrict__ bias,
    float* __restrict__ C, int M){
  (void)M;
  __shared__ float As[32][132];
  __shared__ float Bs[32][132];
  int bm = blockIdx.y * 128;
  int bn = blockIdx.x * 128;
  int tid = threadIdx.x;
  int kk = tid & 31, q = tid >> 5;                 // staging decode (q 0..7)
  int c = (tid & 7) | ((tid & 64) >> 3);           // 0..15
  int r = ((tid >> 3) & 7) | ((tid & 128) >> 4);   // 0..15
  int giA = (2 * r) ^ (r >> 2);                    // G(k=0, col=r*8)
  int giB = (2 * c) ^ (c >> 2);                    // G(k=0, col=c*8)
  float acc[8][8];
#pragma unroll
  for (int ii = 0; ii < 8; ++ii)
#pragma unroll
    for (int jj = 0; jj < 8; ++jj) acc[ii][jj] = 0.f;

  for (int k0 = 0; k0 < 512; k0 += 32){
#pragma unroll
    for (int rr = 0; rr < 4; ++rr){
      int colb = q * 4 + rr * 32;                  // 4-aligned, 0..124
      int gi = (colb >> 2) ^ (colb >> 5) ^ (kk >> 3);
      float4 va, vb;
      va.x = A[(size_t)(bm + colb + 0) * 512 + k0 + kk];
      va.y = A[(size_t)(bm + colb + 1) * 512 + k0 + kk];
      va.z = A[(size_t)(bm + colb + 2) * 512 + k0 + kk];
      va.w = A[(size_t)(bm + colb + 3) * 512 + k0 + kk];
      vb.x = Bw[(size_t)(bn + colb + 0) * 512 + k0 + kk];
      vb.y = Bw[(size_t)(bn + colb + 1) * 512 + k0 + kk];
      vb.z = Bw[(size_t)(bn + colb + 2) * 512 + k0 + kk];
      vb.w = Bw[(size_t)(bn + colb + 3) * 512 + k0 + kk];
      *(float4*)&As[kk][gi << 2] = va;
      *(float4*)&Bs[kk][gi << 2] = vb;
    }
    __syncthreads();
#pragma unroll
    for (int kg = 0; kg < 4; ++kg){
      const int sa = (giA ^ kg) << 2;
      const int sb = (giB ^ kg) << 2;
#pragma unroll
      for (int k8 = 0; k8 < 8; ++k8){
        const int k = kg * 8 + k8;
        float4 av0 = *(const float4*)&As[k][sa];
        float4 av1 = *(const float4*)&As[k][sa ^ 4];
        float4 bv0 = *(const float4*)&Bs[k][sb];
        float4 bv1 = *(const float4*)&Bs[k][sb ^ 4];
        float a[8] = {av0.x, av0.y, av0.z, av0.w, av1.x, av1.y, av1.z, av1.w};
        float b[8] = {bv0.x, bv0.y, bv0.z, bv0.w, bv1.x, bv1.y, bv1.z, bv1.w};
#pragma unroll
        for (int ii = 0; ii < 8; ++ii)
#pragma unroll
          for (int jj = 0; jj < 8; ++jj)
            acc[ii][jj] = __fmaf_rn(a[ii], b[jj], acc[ii][jj]);
      }
    }
    __syncthreads();
  }

  // Epilogue: bias + LDS-staged coalesced stores (r10: avoids L2 RMW).
  float* S = &As[0][0];
  float4 bi0 = *(const float4*)(bias + bn + c * 8);
  float4 bi1 = *(const float4*)(bias + bn + c * 8 + 4);
  int rrow = tid >> 3;
  int f    = tid & 7;
  size_t mr = (size_t)(bm + (rrow >> 1) * 8 + (rrow & 1));
#pragma unroll
  for (int t4 = 0; t4 < 4; ++t4){
#pragma unroll
    for (int p = 0; p < 2; ++p){
      const int ii = t4 * 2 + p;
      const int row = r * 2 + p;
      const int giW = (2 * c) ^ (c >> 2) ^ (row >> 3);
      float4 o0, o1;
      o0.x = __fadd_rn(acc[ii][0], bi0.x);
      o0.y = __fadd_rn(acc[ii][1], bi0.y);
      o0.z = __fadd_rn(acc[ii][2], bi0.z);
      o0.w = __fadd_rn(acc[ii][3], bi0.w);
      o1.x = __fadd_rn(acc[ii][4], bi1.x);
      o1.y = __fadd_rn(acc[ii][5], bi1.y);
      o1.z = __fadd_rn(acc[ii][6], bi1.z);
      o1.w = __fadd_rn(acc[ii][7], bi1.w);
      *(float4*)&S[row * 132 + (giW << 2)] = o0;
      *(float4*)&S[row * 132 + ((giW << 2) ^ 4)] = o1;
    }
    __syncthreads();
#pragma unroll
    for (int u = 0; u < 4; ++u){
      int col4 = 4 * f + 32 * u;
      int giR = (f + 8 * u) ^ u ^ (rrow >> 3);
      float4 v = *(const float4*)&S[rrow * 132 + (giR << 2)];
      *(float4*)&C[(mr + (size_t)t4 * 2) * 1024 + bn + col4] = v;
    }
    __syncthreads();
  }
}

// BN stats: per (chunk, channel), SEQUENTIAL in-order over 256 samples.
// Computes rstd once per (chunk,channel) (r18 hoist) -> bit-exact.
__global__ __launch_bounds__(256) void k_stats_np(const float* __restrict__ A,
    float* __restrict__ mu, float* __restrict__ rstd, int Dch, int c0){
  int cl = blockIdx.x;
  int ch = blockIdx.y * 256 + threadIdx.x;
  const float* base = A + (size_t)cl * 256 * Dch + ch;
  float acc = 0.f;
  for (int s = 0; s < 256; ++s)
    acc = __fadd_rn(acc, base[(size_t)s * Dch]);
  float m = __fmul_rn(acc, 1.f / 256.f);   // /256 exact (pow2)
  float vacc = 0.f;
  for (int s = 0; s < 256; ++s){
    float d = __fsub_rn(base[(size_t)s * Dch], m);
    vacc = __fadd_rn(vacc, __fmul_rn(d, d));
  }
  float var = __fmul_rn(vacc, 1.f / 256.f);
  float ve  = __fadd_rn(var, 1e-5f);
  float sq  = (float)sqrt((double)ve);         // correctly-rounded fp32 sqrt
  float r   = (float)(1.0 / (double)sq);       // correctly-rounded fp32 div
  int c = c0 + cl;
  mu[(size_t)c * Dch + ch]   = m;
  rstd[(size_t)c * Dch + ch] = r;
}

// fp32 BN + LIF scan (hidden layers): spike bitmasks, 64-thread blocks.
// r19: 2-phase even/odd chunk loop; next chunk's h + mu/rstd prefetched
// before processing current chunk (pure load scheduling; bit-exact).
__global__ __launch_bounds__(64) void k_scan_spike_np(const float* __restrict__ A,
    const float* __restrict__ mu, const float* __restrict__ rstd,
    const float* __restrict__ g, const float* __restrict__ bt,
    float* __restrict__ vstate, unsigned long long* __restrict__ mask,
    int Dch, int c0, int nb){
  int ebn = Dch >> 6;
  int eb = blockIdx.x % ebn;
  int b  = blockIdx.x / ebn;
  int e  = (eb << 6) + threadIdx.x;
  float gg = g[e], bb = bt[e];
  float v = vstate[(size_t)b * Dch + e];
  float hA[8], hB[8];
#pragma unroll
  for (int t = 0; t < 8; ++t)
    hA[t] = A[(size_t)(t * 32 + b) * Dch + e];
  float mN = mu[(size_t)c0 * Dch + e];
  float rN = rstd[(size_t)c0 * Dch + e];

  for (int cl = 0; cl < nb; cl += 2){
    // ---- even chunk cl: consumes hA, mN/rN; prefetch chunk cl+1 ----
    {
      float mC = mN, rC = rN;
      if (cl + 1 < nb){
#pragma unroll
        for (int t = 0; t < 8; ++t)
          hB[t] = A[(size_t)(((cl + 1) * 8 + t) * 32 + b) * Dch + e];
        mN = mu[(size_t)(c0 + cl + 1) * Dch + e];
        rN = rstd[(size_t)(c0 + cl + 1) * Dch + e];
      }
#pragma unroll
      for (int t = 0; t < 8; ++t){
        int sl = (cl * 8 + t) * 32 + b;
        float xn = __fadd_rn(__fmul_rn(__fmul_rn(gg, __fsub_rn(hA[t], mC)), rC), bb);
        v = __fadd_rn(v, __fmul_rn(__fsub_rn(xn, v), 0.5f));
        bool sp = (v >= 1.0f);                   // == (v-1>=0)
        unsigned long long bal = __ballot(sp);
        if (sp) v = 0.0f;
        if (threadIdx.x == 0) mask[(size_t)sl * 16 + eb] = bal;
      }
    }
    // ---- odd chunk cl+1: consumes hB, mN/rN; prefetch chunk cl+2 ----
    if (cl + 1 < nb){
      float mC = mN, rC = rN;
      if (cl + 2 < nb){
#pragma unroll
        for (int t = 0; t < 8; ++t)
          hA[t] = A[(size_t)(((cl + 2) * 8 + t) * 32 + b) * Dch + e];
        mN = mu[(size_t)(c0 + cl + 2) * Dch + e];
        rN = rstd[(size_t)(c0 + cl + 2) * Dch + e];
      }
#pragma unroll
      for (int t = 0; t < 8; ++t){
        int sl = ((cl + 1) * 8 + t) * 32 + b;
        float xn = __fadd_rn(__fmul_rn(__fmul_rn(gg, __fsub_rn(hB[t], mC)), rC), bb);
        v = __fadd_rn(v, __fmul_rn(__fsub_rn(xn, v), 0.5f));
        bool sp = (v >= 1.0f);
        unsigned long long bal = __ballot(sp);
        if (sp) v = 0.0f;
        if (threadIdx.x == 0) mask[(size_t)sl * 16 + eb] = bal;
      }
    }
  }
  vstate[(size_t)b * Dch + e] = v;
}

// Sparse spike linear, Eigen order. Wave-cooperative list extraction:
// 16 lanes popcount their 64-bit mask word, __shfl exclusive prefix-scan,
// then parallel ascending writes into LDS. List order identical to the old
// serial scan -> single-accumulator ascending add chain preserved exactly.
// Consume loop: 8 weight rows in flight.
__global__ __launch_bounds__(256) void k_sparse_np(const unsigned long long* __restrict__ mask,
    const float* __restrict__ WT, const float* __restrict__ bias,
    float* __restrict__ C, int Dout){
  int tid = threadIdx.x;
  int lane = tid & 63;
  int wid = tid >> 6;
  int wps = Dout >> 8;            // waves per sample: 4 (1024) or 2 (512)
  int chgrp = wid % wps;
  int sgrp  = wid / wps;
  int spb   = 4 / wps;            // samples per block
  int s = blockIdx.x * spb + sgrp;
  int ch = (chgrp << 8) + (lane << 2);
  __shared__ unsigned short list[2][1024];
  __shared__ int nlist[2];

  if (chgrp == 0 && lane < 16){
    unsigned long long mw = mask[(size_t)s * 16 + lane];
    int cnt = __popcll(mw);
    int base = 0;
#pragma unroll
    for (int w = 0; w < 16; ++w){
      int cw = __shfl(cnt, w, 64);
      base += (w < lane) ? cw : 0;
    }
    int idx = base;
    while (mw){
      int bit = __ffsll(mw) - 1;
      mw &= mw - 1;
      list[sgrp][idx++] = (unsigned short)((lane << 6) + bit);
    }
    if (lane == 15) nlist[sgrp] = base + cnt;
  }
  __syncthreads();
  int n = nlist[sgrp];
  const unsigned short* il = list[sgrp];
  float a0 = 0.f, a1 = 0.f, a2 = 0.f, a3 = 0.f;
  int i = 0;
  for (; i + 8 <= n; i += 8){
    float4 wv[8];
#pragma unroll
    for (int u = 0; u < 8; ++u)
      wv[u] = *(const float4*)(WT + (size_t)il[i + u] * Dout + ch);
#pragma unroll
    for (int u = 0; u < 8; ++u){
      a0 = __fadd_rn(a0, wv[u].x); a1 = __fadd_rn(a1, wv[u].y);
      a2 = __fadd_rn(a2, wv[u].z); a3 = __fadd_rn(a3, wv[u].w);
    }
  }
  for (; i < n; ++i){
    int d = il[i];
    float4 wv = *(const float4*)(WT + (size_t)d * Dout + ch);
    a0 = __fadd_rn(a0, wv.x); a1 = __fadd_rn(a1, wv.y); a2 = __fadd_rn(a2, wv.z); a3 = __fadd_rn(a3, wv.w);
  }
  float4 bb = *(const float4*)(bias + ch);
  float4 o;
  o.x = __fadd_rn(a0, bb.x);
  o.y = __fadd_rn(a1, bb.y);
  o.z = __fadd_rn(a2, bb.z);
  o.w = __fadd_rn(a3, bb.w);
  *(float4*)(C + (size_t)s * Dout + ch) = o;
}

// Last layer: fp32 leaky integrator; sequential mean over 8 timesteps,
// /8 exact; float32 out. r19: same 2-phase prefetch as spike scan.
__global__ __launch_bounds__(64) void k_scan_last_np(const float* __restrict__ A,
    const float* __restrict__ mu, const float* __restrict__ rstd,
    const float* __restrict__ g, const float* __restrict__ bt,
    float* __restrict__ vstate, float* __restrict__ out, int c0, int nb){
  const int Dch = 512;
  int eb = blockIdx.x & 7;
  int b  = blockIdx.x >> 3;
  int e  = (eb << 6) + threadIdx.x;
  float gg = g[e], bb = bt[e];
  float v = vstate[(size_t)b * Dch + e];
  float hA[8], hB[8];
#pragma unroll
  for (int t = 0; t < 8; ++t)
    hA[t] = A[(size_t)(t * 32 + b) * Dch + e];
  float mN = mu[(size_t)c0 * Dch + e];
  float rN = rstd[(size_t)c0 * Dch + e];

  for (int cl = 0; cl < nb; cl += 2){
    // ---- even chunk cl ----
    {
      float mC = mN, rC = rN;
      if (cl + 1 < nb){
#pragma unroll
        for (int t = 0; t < 8; ++t)
          hB[t] = A[(size_t)(((cl + 1) * 8 + t) * 32 + b) * Dch + e];
        mN = mu[(size_t)(c0 + cl + 1) * Dch + e];
        rN = rstd[(size_t)(c0 + cl + 1) * Dch + e];
      }
      float macc = 0.f;
#pragma unroll
      for (int t = 0; t < 8; ++t){
        float xn = __fadd_rn(__fmul_rn(__fmul_rn(gg, __fsub_rn(hA[t], mC)), rC), bb);
        v = __fadd_rn(v, __fmul_rn(__fsub_rn(xn, v), 0.5f));
        macc = __fadd_rn(macc, v);
      }
      out[((size_t)(c0 + cl) * 32 + b) * 512 + e] = __fmul_rn(macc, 0.125f);
    }
    // ---- odd chunk cl+1 ----
    if (cl + 1 < nb){
      float mC = mN, rC = rN;
      if (cl + 2 < nb){
#pragma unroll
        for (int t = 0; t < 8; ++t)
          hA[t] = A[(size_t)(((cl + 2) * 8 + t) * 32 + b) * Dch + e];
        mN = mu[(size_t)(c0 + cl + 2) * Dch + e];
        rN = rstd[(size_t)(c0 + cl + 2) * Dch + e];
      }
      float macc = 0.f;
#pragma unroll
      for (int t = 0; t < 8; ++t){
        float xn = __fadd_rn(__fmul_rn(__fmul_rn(gg, __fsub_rn(hB[t], mC)), rC), bb);
        v = __fadd_rn(v, __fmul_rn(__fsub_rn(xn, v), 0.5f));
        macc = __fadd_rn(macc, v);
      }
      out[((size_t)(c0 + cl + 1) * 32 + b) * 512 + e] = __fmul_rn(macc, 0.125f);
    }
  }
  vstate[(size_t)b * Dch + e] = v;
}

static inline size_t al256(size_t x){ return (x + 255) & ~(size_t)255; }

extern "C" void kernel_launch(void* const* d_in, const int* in_sizes, int n_in,
                              void* d_out, int out_size, void* d_ws, size_t ws_size,
                              hipStream_t stream){
  (void)in_sizes; (void)n_in; (void)out_size;
  const float* x   = (const float*)d_in[0];
  const float* W0  = (const float*)d_in[1];
  const float* b0  = (const float*)d_in[2];
  const float* g0  = (const float*)d_in[3];
  const float* bt0 = (const float*)d_in[4];
  const float* W1  = (const float*)d_in[5];
  const float* b1  = (const float*)d_in[6];
  const float* g1  = (const float*)d_in[7];
  const float* bt1 = (const float*)d_in[8];
  const float* W2  = (const float*)d_in[9];
  const float* b2  = (const float*)d_in[10];
  const float* g2  = (const float*)d_in[11];
  const float* bt2 = (const float*)d_in[12];
  float* out = (float*)d_out;   // reference output dtype: float32

  char* p = (char*)d_ws;
  auto carve = [&](size_t bytes)->char*{ char* q = p; p += al256(bytes); return q; };
  float* W1T  = (float*)carve((size_t)1024 * 1024 * 4);   // [d=1024][e=1024]
  float* W2T  = (float*)carve((size_t)1024 * 512 * 4);    // [d=1024][e=512]
  float* mu0  = (float*)carve((size_t)128 * 1024 * 4);
  float* rs0  = (float*)carve((size_t)128 * 1024 * 4);
  float* mu1  = (float*)carve((size_t)128 * 1024 * 4);
  float* rs1  = (float*)carve((size_t)128 * 1024 * 4);
  float* mu2  = (float*)carve((size_t)128 * 512 * 4);
  float* rs2  = (float*)carve((size_t)128 * 512 * 4);
  float* v0   = (float*)carve((size_t)32 * 1024 * 4);
  float* v1   = (float*)carve((size_t)32 * 1024 * 4);
  float* v2   = (float*)carve((size_t)32 * 512 * 4);
  size_t fixed_used = (size_t)(p - (char*)d_ws);

  auto need = [&](int nb)->size_t{
    return al256((size_t)nb * 256 * 1024 * 4)        // fp32 activation buffer
         + 2 * al256((size_t)nb * 256 * 16 * 8);     // mask0, mask1
  };
  int NB = 128;
  while (NB > 1 && fixed_used + need(NB) > ws_size) NB >>= 1;
  if (fixed_used + need(NB) > ws_size) return;

  float*              a_buf = (float*)carve((size_t)NB * 256 * 1024 * 4);
  unsigned long long* mask0 = (unsigned long long*)carve((size_t)NB * 256 * 16 * 8);
  unsigned long long* mask1 = (unsigned long long*)carve((size_t)NB * 256 * 16 * 8);

  // zero v-states (carved contiguously: 32*(1024+1024+512) floats)
  {
    int nz = 32 * (1024 + 1024 + 512);
    k_zero<<<dim3((nz + 255) / 256), dim3(256), 0, stream>>>((unsigned int*)v0, nz);
  }
  k_transpose<<<dim3(32, 32), dim3(32, 8), 0, stream>>>(W1, W1T, 1024, 1024);
  k_transpose<<<dim3(32, 16), dim3(32, 8), 0, stream>>>(W2, W2T, 512, 1024);

  int nblk = 128 / NB;
  for (int cb = 0; cb < nblk; ++cb){
    int c0 = cb * NB;
    int M = NB * 256;
    const float* xblk = x + (size_t)c0 * 256 * 512;

    // Layer 0 (Eigen-order FMA GEMM; n-tile-major grid for x L2 reuse)
    k_gemm_np<<<dim3(8, M / 128), dim3(256), 0, stream>>>(xblk, W0, b0, a_buf, M);
    k_stats_np<<<dim3(NB, 4), dim3(256), 0, stream>>>(a_buf, mu0, rs0, 1024, c0);
    k_scan_spike_np<<<dim3(32 * 16), dim3(64), 0, stream>>>(a_buf, mu0, rs0, g0, bt0, v0, mask0, 1024, c0, NB);

    // Layer 1 (sparse, ascending single-chain, batched loads)
    k_sparse_np<<<dim3(M), dim3(256), 0, stream>>>(mask0, W1T, b1, a_buf, 1024);
    k_stats_np<<<dim3(NB, 4), dim3(256), 0, stream>>>(a_buf, mu1, rs1, 1024, c0);
    k_scan_spike_np<<<dim3(32 * 16), dim3(64), 0, stream>>>(a_buf, mu1, rs1, g1, bt1, v1, mask1, 1024, c0, NB);

    // Layer 2 (sparse) + integrator output
    k_sparse_np<<<dim3(M / 2), dim3(256), 0, stream>>>(mask1, W2T, b2, a_buf, 512);
    k_stats_np<<<dim3(NB, 2), dim3(256), 0, stream>>>(a_buf, mu2, rs2, 512, c0);
    k_scan_last_np<<<dim3(32 * 8), dim3(64), 0, stream>>>(a_buf, mu2, rs2, g2, bt2, v2, out, c0, NB);
  }
}